// Round 1
// baseline (236.505 us; speedup 1.0000x reference)
//
#include <hip/hip_runtime.h>

#define OC    96
#define KK    147   // 3*7*7
#define IH    224
#define IW    224
#define OHH   112
#define OWW   112
#define NIMG  16

// ---------------- K1: weight RMS renorm + transpose to [147][96] ----------------
__global__ __launch_bounds__(64) void renorm_kernel(const float* __restrict__ w,
                                                    float* __restrict__ wt) {
    int oc = blockIdx.x;
    int l  = threadIdx.x;
    float ssq = 0.f;
    for (int k = l; k < KK; k += 64) {
        float v = w[oc * KK + k];
        ssq += v * v;
    }
    #pragma unroll
    for (int off = 32; off > 0; off >>= 1) ssq += __shfl_xor(ssq, off, 64);
    float rms   = sqrtf(ssq * (1.0f / 147.0f));
    float scale = (rms > 0.1f) ? (0.1f / rms) : 1.0f;
    for (int k = l; k < KK; k += 64) wt[k * OC + oc] = w[oc * KK + k] * scale;
}

// ---------------- K2: 7x7 stride-2 conv, LDS-staged input patch ----------------
// Block: 256 threads = 32(w) x 8(h) output tile; 8 out-channels per thread.
// Weights are k-major [147][96] so all weight reads are wave-uniform -> s_load.
#define CTW 32
#define CTH 8
#define OCPT 8
#define PATCH_W 70   // 69 used, padded for float2 alignment
#define PATCH_H 21

__global__ __launch_bounds__(256) void conv_kernel(const float* __restrict__ x,
                                                   const float* __restrict__ wt,
                                                   const float* __restrict__ bias,
                                                   float* __restrict__ y) {
    __shared__ float sx[3 * PATCH_H * PATCH_W];
    const int tid = threadIdx.x;
    const int tx = tid & 31, ty = tid >> 5;
    const int tile = blockIdx.x;           // 0..55 : 4 tiles wide x 14 tiles high
    const int w0 = (tile & 3) * CTW;
    const int h0 = (tile >> 2) * CTH;
    const int oc0 = blockIdx.y * OCPT;
    const int img = blockIdx.z;
    const int ih0 = 2 * h0 - 3, iw0 = 2 * w0 - 3;
    const float* xim = x + (size_t)img * 3 * IH * IW;

    for (int i = tid; i < 3 * PATCH_H * PATCH_W; i += 256) {
        int c   = i / (PATCH_H * PATCH_W);
        int rem = i - c * (PATCH_H * PATCH_W);
        int r   = rem / PATCH_W;
        int cc  = rem - r * PATCH_W;
        int ih = ih0 + r, iw = iw0 + cc;
        float v = 0.f;
        if (cc < 69 && (unsigned)ih < IH && (unsigned)iw < IW)
            v = xim[(c * IH + ih) * IW + iw];
        sx[i] = v;
    }
    __syncthreads();

    float acc[OCPT];
    #pragma unroll
    for (int o = 0; o < OCPT; o++) acc[o] = bias[oc0 + o];

    #pragma unroll
    for (int c = 0; c < 3; c++) {
        #pragma unroll
        for (int kh = 0; kh < 7; kh++) {
            const float* row = &sx[(c * PATCH_H + 2 * ty + kh) * PATCH_W + 2 * tx];
            const float2* row2 = reinterpret_cast<const float2*>(row); // 8B aligned
            float2 p0 = row2[0], p1 = row2[1], p2 = row2[2], p3 = row2[3];
            float xv[8] = {p0.x, p0.y, p1.x, p1.y, p2.x, p2.y, p3.x, p3.y};
            const float* wk = &wt[(c * 49 + kh * 7) * OC + oc0];
            #pragma unroll
            for (int kw = 0; kw < 7; kw++) {
                #pragma unroll
                for (int o = 0; o < OCPT; o++)
                    acc[o] = fmaf(xv[kw], wk[kw * OC + o], acc[o]);
            }
        }
    }

    const int oh = h0 + ty, ow = w0 + tx;
    if (ow < OWW) {
        float* yp = y + (((size_t)img * OC + oc0) * OHH + oh) * OWW + ow;
        #pragma unroll
        for (int o = 0; o < OCPT; o++) yp[(size_t)o * (OHH * OWW)] = acc[o];
    }
}

// ---------------- K3: fused LCN (two 5x5 boxes) + relu + 2x2 maxpool ----------------
// One block per 32x32 pre_pool tile per plane. Separable 5-tap sums in LDS.
__global__ __launch_bounds__(256) void lcn_pool_kernel(const float* __restrict__ y,
                                                       float* __restrict__ outp,
                                                       float* __restrict__ prep,
                                                       float* __restrict__ idxp) {
    __shared__ float sy[40 * 41];     // y tile + halo 4
    __shared__ float srow[40 * 37];   // horizontal 5-sum of y
    __shared__ float scent[36 * 37];  // centered (zeroed outside image)
    __shared__ float sc2r[36 * 33];   // horizontal 5-sum of centered^2
    __shared__ float spre[32 * 33];   // relu'd normalized tile
    const int tid  = threadIdx.x;
    const int tile = blockIdx.x;                // 0..15
    const int gx0 = (tile & 3) * 32;
    const int gy0 = (tile >> 2) * 32;
    const int plane = blockIdx.y;               // img*96 + ch
    const float* yp = y + (size_t)plane * (OHH * OWW);

    for (int i = tid; i < 40 * 40; i += 256) {
        int r = i / 40, c = i - r * 40;
        int gy = gy0 + r - 4, gx = gx0 + c - 4;
        float v = 0.f;
        if ((unsigned)gy < OHH && (unsigned)gx < OWW) v = yp[gy * OWW + gx];
        sy[r * 41 + c] = v;
    }
    __syncthreads();

    for (int i = tid; i < 40 * 36; i += 256) {
        int r = i / 36, cc = i - r * 36;
        const float* b = &sy[r * 41 + cc];
        srow[r * 37 + cc] = b[0] + b[1] + b[2] + b[3] + b[4];
    }
    __syncthreads();

    for (int i = tid; i < 36 * 36; i += 256) {
        int rr = i / 36, cc = i - rr * 36;
        const float* b = &srow[rr * 37 + cc];
        float m = (b[0] + b[37] + b[74] + b[111] + b[148]) * 0.04f;
        int gy = gy0 + rr - 2, gx = gx0 + cc - 2;
        float cent = 0.f;
        if ((unsigned)gy < OHH && (unsigned)gx < OWW)
            cent = sy[(rr + 2) * 41 + cc + 2] - m;   // zero outside image
        scent[rr * 37 + cc] = cent;
    }
    __syncthreads();

    for (int i = tid; i < 36 * 32; i += 256) {
        int rr = i / 32, c3 = i - rr * 32;
        const float* b = &scent[rr * 37 + c3];
        sc2r[rr * 33 + c3] = b[0]*b[0] + b[1]*b[1] + b[2]*b[2] + b[3]*b[3] + b[4]*b[4];
    }
    __syncthreads();

    for (int i = tid; i < 32 * 32; i += 256) {
        int r4 = i / 32, c3 = i - r4 * 32;
        const float* b = &sc2r[r4 * 33 + c3];
        float var  = (b[0] + b[33] + b[66] + b[99] + b[132]) * 0.04f;
        float cent = scent[(r4 + 2) * 37 + c3 + 2];
        float val  = cent * rsqrtf(var + 1.0f);
        val = fmaxf(val, 0.f);
        spre[r4 * 33 + c3] = val;
        int gy = gy0 + r4, gx = gx0 + c3;
        if (gy < OHH && gx < OWW)
            prep[(size_t)plane * (OHH * OWW) + gy * OWW + gx] = val;
    }
    __syncthreads();

    {   // 2x2 maxpool, first-max-wins argmax, torch flat index into 112x112 plane
        int hp = tid >> 4, wp = tid & 15;
        int gy = gy0 + 2 * hp, gx = gx0 + 2 * wp;
        if (gy + 1 < OHH && gx + 1 < OWW) {
            float v0 = spre[(2*hp)     * 33 + 2*wp];
            float v1 = spre[(2*hp)     * 33 + 2*wp + 1];
            float v2 = spre[(2*hp + 1) * 33 + 2*wp];
            float v3 = spre[(2*hp + 1) * 33 + 2*wp + 1];
            float best = v0; int loc = 0;
            if (v1 > best) { best = v1; loc = 1; }
            if (v2 > best) { best = v2; loc = 2; }
            if (v3 > best) { best = v3; loc = 3; }
            int oh = gy >> 1, ow = gx >> 1;
            int idx = (gy + (loc >> 1)) * OWW + (gx + (loc & 1));
            size_t oidx = (size_t)plane * (56 * 56) + oh * 56 + ow;
            outp[oidx] = best;
            idxp[oidx] = (float)idx;   // whole d_out read back as float32
        }
    }
}

extern "C" void kernel_launch(void* const* d_in, const int* in_sizes, int n_in,
                              void* d_out, int out_size, void* d_ws, size_t ws_size,
                              hipStream_t stream) {
    const float* x    = (const float*)d_in[0];
    const float* w    = (const float*)d_in[1];
    const float* bias = (const float*)d_in[2];

    float* y  = (float*)d_ws;                                   // 19,267,584 f32
    float* wt = y + (size_t)NIMG * OC * OHH * OWW;              // 14,112 f32

    float* outp = (float*)d_out;                                // [16,96,56,56]
    float* prep = outp + (size_t)NIMG * OC * 56 * 56;           // [16,96,112,112]
    float* idxp = prep + (size_t)NIMG * OC * OHH * OWW;         // [16,96,56,56]

    renorm_kernel<<<dim3(OC), dim3(64), 0, stream>>>(w, wt);
    conv_kernel<<<dim3(56, 12, NIMG), dim3(256), 0, stream>>>(x, wt, bias, y);
    lcn_pool_kernel<<<dim3(16, NIMG * OC), dim3(256), 0, stream>>>(y, outp, prep, idxp);
}